// Round 1
// baseline (1033.692 us; speedup 1.0000x reference)
//
#include <hip/hip_runtime.h>

// Problem constants (match reference)
constexpr int N_NODES = 50000;
constexpr int C_IN    = 32;
constexpr int H_HID   = 32;
constexpr int E_EDGES = 1600000;
constexpr int NH      = N_NODES * H_HID;   // 1,600,000
constexpr float BN_EPS = 1e-5f;

// ---------------------------------------------------------------- zero scratch
__global__ void zero_kernel(float4* __restrict__ p, int n4) {
    int i = blockIdx.x * blockDim.x + threadIdx.x;
    if (i < n4) p[i] = make_float4(0.f, 0.f, 0.f, 0.f);
}

// ---------------------------------------------------------------- BatchNorm1d (eval)
__global__ void bn_kernel(const float* __restrict__ x,
                          const float* __restrict__ gamma,
                          const float* __restrict__ beta,
                          const float* __restrict__ mean,
                          const float* __restrict__ var,
                          float* __restrict__ xn) {
    __shared__ float s_scale[32], s_shift[32];
    int tid = threadIdx.x;
    if (tid < 32) {
        float sc = gamma[tid] * rsqrtf(var[tid] + BN_EPS);
        s_scale[tid] = sc;
        s_shift[tid] = beta[tid] - mean[tid] * sc;
    }
    __syncthreads();
    int i  = blockIdx.x * blockDim.x + tid;
    int n4 = N_NODES * C_IN / 4;
    if (i < n4) {
        float4 v = ((const float4*)x)[i];
        int c = (i * 4) & 31;   // row-major [N,32]: 4 consecutive channels
        v.x = fmaf(v.x, s_scale[c + 0], s_shift[c + 0]);
        v.y = fmaf(v.y, s_scale[c + 1], s_shift[c + 1]);
        v.z = fmaf(v.z, s_scale[c + 2], s_shift[c + 2]);
        v.w = fmaf(v.w, s_scale[c + 3], s_shift[c + 3]);
        ((float4*)xn)[i] = v;
    }
}

// ---------------------------------------------------------------- edge scatter-add
// One thread per (edge, channel); 32 lanes share an edge -> coalesced 128B row
// gather from xn (6.4MB, L2/LLC resident). agg gets w_e * x[src]; agg0 gets the
// self-loop (T_0) term, rare (~E/N edges) so the branch is near-uniform.
__global__ void scatter_kernel(const float* __restrict__ xn,
                               const int*   __restrict__ ei,
                               const float* __restrict__ ew,
                               float* __restrict__ agg,
                               float* __restrict__ agg0) {
    int gid = blockIdx.x * blockDim.x + threadIdx.x;
    int e = gid >> 5;
    int c = gid & 31;
    if (e < E_EDGES) {
        int   src = ei[e];
        int   dst = ei[E_EDGES + e];
        float w   = ew[e];
        float v   = xn[src * 32 + c];
        atomicAdd(&agg[dst * 32 + c], w * v);
        if (src == dst) atomicAdd(&agg0[dst * 32 + c], v);
    }
}

// ---------------------------------------------------------------- per-node contraction
// result[n,h] = relu( sum_c agg[n,c]*(W1+W2)[c,h] + agg0[n,c]*W0[c,h] )
__global__ void node_kernel(const float* __restrict__ agg,
                            const float* __restrict__ agg0,
                            const float* __restrict__ W,
                            float* __restrict__ rres) {
    __shared__ float s_w0[1024], s_wsum[1024];
    for (int idx = threadIdx.x; idx < 1024; idx += blockDim.x) {
        s_w0[idx]   = W[idx];
        s_wsum[idx] = W[1024 + idx] + W[2048 + idx];
    }
    __syncthreads();
    int gid = blockIdx.x * blockDim.x + threadIdx.x;
    if (gid < NH) {
        int n = gid >> 5, h = gid & 31;
        const float* ar = agg  + n * 32;
        const float* a0 = agg0 + n * 32;
        float a = 0.f;
#pragma unroll
        for (int c = 0; c < 32; c++) {
            a = fmaf(ar[c], s_wsum[c * 32 + h], a);  // lanes h=0..31 -> banks 0..31
            a = fmaf(a0[c], s_w0  [c * 32 + h], a);
        }
        rres[gid] = fmaxf(a, 0.f);
    }
}

// ---------------------------------------------------------------- fc1: [1,NH] @ [NH,64]
// 625 blocks x 2560-float chunks (NH = 625*2560 exactly). Each wave owns 16 of
// the 64 outputs and sweeps the whole chunk with float4 loads (16B/lane,
// coalesced per j-row since fc1_w is row-major [64, NH]).
constexpr int CHUNK = 2560;              // floats per block
__global__ void fc1_kernel(const float* __restrict__ r,
                           const float* __restrict__ w,
                           float* __restrict__ hacc) {
    int tid  = threadIdx.x;
    int wave = tid >> 6, lane = tid & 63;
    size_t ib = (size_t)blockIdx.x * CHUNK;

    const float4* r4 = (const float4*)(r + ib);
    float4 rr[10];
#pragma unroll
    for (int k = 0; k < 10; k++) rr[k] = r4[lane + k * 64];   // 640 float4 = chunk

    int j0 = wave * 16;
    float acc[16];
#pragma unroll
    for (int jj = 0; jj < 16; jj++) {
        const float4* w4 = (const float4*)(w + (size_t)(j0 + jj) * NH + ib);
        float a = 0.f;
#pragma unroll
        for (int k = 0; k < 10; k++) {
            float4 ww = w4[lane + k * 64];
            a = fmaf(rr[k].x, ww.x, a);
            a = fmaf(rr[k].y, ww.y, a);
            a = fmaf(rr[k].z, ww.z, a);
            a = fmaf(rr[k].w, ww.w, a);
        }
        acc[jj] = a;
    }
#pragma unroll
    for (int jj = 0; jj < 16; jj++) {
        float a = acc[jj];
#pragma unroll
        for (int off = 32; off > 0; off >>= 1) a += __shfl_down(a, off);
        if (lane == 0) atomicAdd(&hacc[j0 + jj], a);   // 625 adds per output
    }
}

// ---------------------------------------------------------------- head: relu + fc2
__global__ void head_kernel(const float* __restrict__ hacc,
                            const float* __restrict__ fc1_b,
                            const float* __restrict__ fc2_w,
                            const float* __restrict__ fc2_b,
                            float* __restrict__ out) {
    int j = threadIdx.x;                       // 64 threads = 1 wave
    float hj = fmaxf(hacc[j] + fc1_b[j], 0.f);
#pragma unroll
    for (int k = 0; k < 2; k++) {
        float p = hj * fc2_w[k * 64 + j];
#pragma unroll
        for (int off = 32; off > 0; off >>= 1) p += __shfl_down(p, off);
        if (j == 0) out[k] = p + fc2_b[k];
    }
}

// ---------------------------------------------------------------- launch
extern "C" void kernel_launch(void* const* d_in, const int* in_sizes, int n_in,
                              void* d_out, int out_size, void* d_ws, size_t ws_size,
                              hipStream_t stream) {
    const float* x     = (const float*)d_in[0];
    const float* ew    = (const float*)d_in[1];
    const float* W     = (const float*)d_in[2];
    const float* gamma = (const float*)d_in[3];
    const float* beta  = (const float*)d_in[4];
    const float* mean  = (const float*)d_in[5];
    const float* var   = (const float*)d_in[6];
    const float* fc1_w = (const float*)d_in[7];
    const float* fc1_b = (const float*)d_in[8];
    const float* fc2_w = (const float*)d_in[9];
    const float* fc2_b = (const float*)d_in[10];
    const int*   ei    = (const int*)d_in[11];
    float* out = (float*)d_out;

    // workspace layout (floats): agg | agg0 | hacc(64) | xn | rres  = 25.6 MB
    float* agg  = (float*)d_ws;
    float* agg0 = agg  + NH;
    float* hacc = agg0 + NH;
    float* xn   = hacc + 64;
    float* rres = xn   + NH;

    {   // zero agg, agg0, hacc in one pass (contiguous 2*NH+64 floats, %4==0)
        int n4 = (2 * NH + 64) / 4;
        zero_kernel<<<(n4 + 255) / 256, 256, 0, stream>>>((float4*)agg, n4);
    }
    bn_kernel<<<(N_NODES * C_IN / 4 + 255) / 256, 256, 0, stream>>>(
        x, gamma, beta, mean, var, xn);
    scatter_kernel<<<(E_EDGES * 32) / 256, 256, 0, stream>>>(xn, ei, ew, agg, agg0);
    node_kernel<<<(NH + 255) / 256, 256, 0, stream>>>(agg, agg0, W, rres);
    fc1_kernel<<<NH / CHUNK, 256, 0, stream>>>(rres, fc1_w, hacc);
    head_kernel<<<1, 64, 0, stream>>>(hacc, fc1_b, fc2_w, fc2_b, out);
}

// Round 2
// 976.806 us; speedup vs baseline: 1.0582x; 1.0582x over previous
//
#include <hip/hip_runtime.h>

constexpr int N_NODES = 50000;
constexpr int E_EDGES = 1600000;
constexpr int NH      = N_NODES * 32;   // 1,600,000
constexpr float BN_EPS = 1e-5f;

// ---------------------------------------------------------------- zero scratch
__global__ void zero_kernel(float4* __restrict__ p, int n4) {
    int i = blockIdx.x * blockDim.x + threadIdx.x;
    if (i < n4) p[i] = make_float4(0.f, 0.f, 0.f, 0.f);
}

// ---------------------------------------------------------------- CSR build
__global__ void hist_kernel(const int* __restrict__ ei, int* __restrict__ counts) {
    int e = blockIdx.x * blockDim.x + threadIdx.x;
    if (e < E_EDGES) atomicAdd(&counts[ei[E_EDGES + e]], 1);
}

// block-wide exclusive scan helper (256 threads, Hillis-Steele in LDS)
__device__ inline int block_excl_scan(int v, int* s) {
    int t = threadIdx.x;
    s[t] = v;
    __syncthreads();
    for (int d = 1; d < 256; d <<= 1) {
        int x = (t >= d) ? s[t - d] : 0;
        __syncthreads();
        s[t] += x;
        __syncthreads();
    }
    return s[t] - v;   // exclusive
}

__global__ void scan1_kernel(const int* __restrict__ counts, int* __restrict__ bsum) {
    int i = blockIdx.x * 256 + threadIdx.x;
    int v = (i < N_NODES) ? counts[i] : 0;
#pragma unroll
    for (int o = 32; o > 0; o >>= 1) v += __shfl_down(v, o);
    __shared__ int s[4];
    int wave = threadIdx.x >> 6, lane = threadIdx.x & 63;
    if (lane == 0) s[wave] = v;
    __syncthreads();
    if (threadIdx.x == 0) bsum[blockIdx.x] = s[0] + s[1] + s[2] + s[3];
}

__global__ void scan2_kernel(int* __restrict__ bsum) {   // 1 block, 256 threads
    __shared__ int s[256];
    int t = threadIdx.x;
    int v = (t < 196) ? bsum[t] : 0;
    int excl = block_excl_scan(v, s);
    if (t < 196) bsum[t] = excl;
}

__global__ void scan3_kernel(const int* __restrict__ counts, const int* __restrict__ bsum,
                             int* __restrict__ off, int* __restrict__ cursor) {
    __shared__ int s[256];
    int i = blockIdx.x * 256 + threadIdx.x;
    int v = (i < N_NODES) ? counts[i] : 0;
    int excl = block_excl_scan(v, s) + bsum[blockIdx.x];
    if (i < N_NODES) { off[i] = excl; cursor[i] = excl; }
    if (i == N_NODES - 1) off[N_NODES] = excl + v;   // == E
}

__global__ void place_kernel(const int* __restrict__ ei, const float* __restrict__ ew,
                             int* __restrict__ cursor,
                             int* __restrict__ srcs_s, float* __restrict__ ws_s) {
    int e = blockIdx.x * blockDim.x + threadIdx.x;
    if (e < E_EDGES) {
        int src = ei[e];
        int dst = ei[E_EDGES + e];
        int pos = atomicAdd(&cursor[dst], 1);
        srcs_s[pos] = src | ((src == dst) ? 0x80000000 : 0);
        ws_s[pos]   = ew[e];
    }
}

// ---------------------------------------------------------------- fused gather:
// BN (inline per-lane scale/shift) + weighted neighbor sum + 32x32 W-contraction
// + relu. 32 lanes per node (c = lane&31), 8 nodes per 256-thread block.
__global__ void gather_kernel(const float* __restrict__ x,
                              const float* __restrict__ gamma,
                              const float* __restrict__ beta,
                              const float* __restrict__ mean,
                              const float* __restrict__ var,
                              const int*   __restrict__ off,
                              const int*   __restrict__ srcs_s,
                              const float* __restrict__ ws_s,
                              const float* __restrict__ W,
                              float* __restrict__ rres) {
    __shared__ float s_w0[1024], s_wsum[1024];
    int tid = threadIdx.x;
    for (int idx = tid; idx < 1024; idx += 256) {
        s_w0[idx]   = W[idx];
        s_wsum[idx] = W[1024 + idx] + W[2048 + idx];
    }
    __syncthreads();

    int n     = blockIdx.x * 8 + (tid >> 5);  // 6250*8 = 50000 exactly
    int c     = tid & 31;
    int gbase = tid & 32;                     // this group's base lane within the wave

    float sc = gamma[c] * rsqrtf(var[c] + BN_EPS);
    float sh = beta[c] - mean[c] * sc;

    int e0 = off[n], e1 = off[n + 1];
    int nb = e1 - e0;
    float acc = 0.f, acc0 = 0.f;
    for (int base = 0; base < nb; base += 32) {
        int   me = base + c;
        int   sw = 0; float wv = 0.f;
        if (me < nb) { sw = srcs_s[e0 + me]; wv = ws_s[e0 + me]; }
        int m = min(32, nb - base);
#pragma unroll 4
        for (int j = 0; j < m; j++) {
            int   swj = __shfl(sw, gbase + j);
            float wj  = __shfl(wv, gbase + j);
            int   src = swj & 0x7fffffff;
            float v   = fmaf(x[src * 32 + c], sc, sh);
            acc = fmaf(wj, v, acc);
            if (swj < 0) acc0 += v;
        }
    }
    // contraction: result[n,h] = relu(sum_c acc_c*Wsum[c,h] + acc0_c*W0[c,h]), h = c
    float r = 0.f;
#pragma unroll
    for (int cc = 0; cc < 32; cc++) {
        float a  = __shfl(acc,  gbase + cc);
        float a0 = __shfl(acc0, gbase + cc);
        r = fmaf(a,  s_wsum[cc * 32 + c], r);
        r = fmaf(a0, s_w0  [cc * 32 + c], r);
    }
    rres[n * 32 + c] = fmaxf(r, 0.f);
}

// ---------------------------------------------------------------- fc1: [1,NH] @ [NH,64]^T
// r chunk staged in LDS (no big register arrays -> no spill). Each wave owns 16
// outputs, processed 2 at a time (20 independent 16B loads in flight).
constexpr int CHUNK = 2560;   // 640 float4; NH/CHUNK = 625 blocks
__global__ void fc1_kernel(const float* __restrict__ r,
                           const float* __restrict__ w,
                           float* __restrict__ hacc) {
    __shared__ float4 s_r[640];
    int tid = threadIdx.x;
    size_t ib = (size_t)blockIdx.x * CHUNK;
    const float4* r4 = (const float4*)(r + ib);
    for (int i = tid; i < 640; i += 256) s_r[i] = r4[i];
    __syncthreads();

    int wave = tid >> 6, lane = tid & 63;
    int jbase = wave * 16;
    for (int jj = 0; jj < 16; jj += 2) {
        const float4* wa = (const float4*)(w + (size_t)(jbase + jj    ) * NH + ib);
        const float4* wb = (const float4*)(w + (size_t)(jbase + jj + 1) * NH + ib);
        float a0 = 0.f, a1 = 0.f;
#pragma unroll
        for (int k = 0; k < 10; k++) {
            float4 rv = s_r[lane + k * 64];
            float4 x0 = wa[lane + k * 64];
            float4 x1 = wb[lane + k * 64];
            a0 = fmaf(rv.x, x0.x, a0); a0 = fmaf(rv.y, x0.y, a0);
            a0 = fmaf(rv.z, x0.z, a0); a0 = fmaf(rv.w, x0.w, a0);
            a1 = fmaf(rv.x, x1.x, a1); a1 = fmaf(rv.y, x1.y, a1);
            a1 = fmaf(rv.z, x1.z, a1); a1 = fmaf(rv.w, x1.w, a1);
        }
#pragma unroll
        for (int o = 32; o > 0; o >>= 1) {
            a0 += __shfl_down(a0, o);
            a1 += __shfl_down(a1, o);
        }
        if (lane == 0) {
            atomicAdd(&hacc[jbase + jj    ], a0);
            atomicAdd(&hacc[jbase + jj + 1], a1);
        }
    }
}

// ---------------------------------------------------------------- head: relu + fc2
__global__ void head_kernel(const float* __restrict__ hacc,
                            const float* __restrict__ fc1_b,
                            const float* __restrict__ fc2_w,
                            const float* __restrict__ fc2_b,
                            float* __restrict__ out) {
    int j = threadIdx.x;   // 64 threads = 1 wave
    float hj = fmaxf(hacc[j] + fc1_b[j], 0.f);
#pragma unroll
    for (int k = 0; k < 2; k++) {
        float p = hj * fc2_w[k * 64 + j];
#pragma unroll
        for (int o = 32; o > 0; o >>= 1) p += __shfl_down(p, o);
        if (j == 0) out[k] = p + fc2_b[k];
    }
}

// ---------------------------------------------------------------- launch
extern "C" void kernel_launch(void* const* d_in, const int* in_sizes, int n_in,
                              void* d_out, int out_size, void* d_ws, size_t ws_size,
                              hipStream_t stream) {
    const float* x     = (const float*)d_in[0];
    const float* ew    = (const float*)d_in[1];
    const float* W     = (const float*)d_in[2];
    const float* gamma = (const float*)d_in[3];
    const float* beta  = (const float*)d_in[4];
    const float* mean  = (const float*)d_in[5];
    const float* var   = (const float*)d_in[6];
    const float* fc1_w = (const float*)d_in[7];
    const float* fc1_b = (const float*)d_in[8];
    const float* fc2_w = (const float*)d_in[9];
    const float* fc2_b = (const float*)d_in[10];
    const int*   ei    = (const int*)d_in[11];
    float* out = (float*)d_out;

    // ws layout (4B elems): hacc(64) | counts(50016) | off(50016) | cursor(50016)
    //                       | bsum(256) | srcs_s(E) | ws_s(E) | rres(NH)  ~ 19.8 MB
    constexpr int NPAD = 50016;
    float* hacc   = (float*)d_ws;
    int*   counts = (int*)d_ws + 64;
    int*   off    = (int*)d_ws + 64 + NPAD;
    int*   cursor = (int*)d_ws + 64 + 2 * NPAD;
    int*   bsum   = (int*)d_ws + 64 + 3 * NPAD;
    int*   srcs_s = bsum + 256;
    float* ws_s   = (float*)(srcs_s + E_EDGES);
    float* rres   = ws_s + E_EDGES;
    (void)ws_size; (void)in_sizes; (void)n_in; (void)out_size;

    {   // zero hacc + counts (contiguous 64 + 50016 elems, %4 == 0)
        int n4 = (64 + NPAD) / 4;
        zero_kernel<<<(n4 + 255) / 256, 256, 0, stream>>>((float4*)d_ws, n4);
    }
    hist_kernel <<<(E_EDGES + 255) / 256, 256, 0, stream>>>(ei, counts);
    scan1_kernel<<<196, 256, 0, stream>>>(counts, bsum);
    scan2_kernel<<<1,   256, 0, stream>>>(bsum);
    scan3_kernel<<<196, 256, 0, stream>>>(counts, bsum, off, cursor);
    place_kernel<<<(E_EDGES + 255) / 256, 256, 0, stream>>>(ei, ew, cursor, srcs_s, ws_s);
    gather_kernel<<<N_NODES / 8, 256, 0, stream>>>(x, gamma, beta, mean, var,
                                                   off, srcs_s, ws_s, W, rres);
    fc1_kernel <<<NH / CHUNK, 256, 0, stream>>>(rres, fc1_w, hacc);
    head_kernel<<<1, 64, 0, stream>>>(hacc, fc1_b, fc2_w, fc2_b, out);
}